// Round 8
// baseline (337.275 us; speedup 1.0000x reference)
//
#include <hip/hip_runtime.h>
#include <hip/hip_bf16.h>

typedef unsigned short u16;
typedef unsigned int   u32;
typedef short bf16x8 __attribute__((ext_vector_type(8)));
typedef float f32x4  __attribute__((ext_vector_type(4)));

#define O_N    4
#define D_K    128
#define D_V    512
#define BANK   7200
#define NQ     3600
#define NT     64            // query columns per block
#define NTILES 57            // ceil(3600/64)
#define NSUB   225           // 7200 / 32 sub-tiles
#define VH_ROWS 256          // v rows per block (half of 512)

// ---- LDS layout (bytes)
#define K_OFF    0           // K dbuf: 2 x [64 b][128 d] bf16 (2 x 16384)
#define P_OFF    32768       // P dbuf: 2 x [64 n][64 b] bf16, 128B rows (2 x 8192)
#define LMM_OFF  49152       // l[64], mm[64] f32 (512)
#define SMEM_BYTES 49664
#define Q_OFF    0           // Q tile [64 n][128 d] bf16 (16KB) overlaps K buf0; prologue only

// global_load_lds: linear LDS dest (wave base + lane*16); source address is
// pre-permuted per-lane so READ-side swizzle formulas keep working.
// NOTE: imm offset is 13-bit SIGNED (max +4095) — keep 0, explicit addresses.
#define GLL(gsrc, ldst) __builtin_amdgcn_global_load_lds( \
    (const __attribute__((address_space(1))) void*)(gsrc), \
    (__attribute__((address_space(3))) void*)(ldst), 16, 0, 0)

#define MFMA16(a, b, c) __builtin_amdgcn_mfma_f32_16x16x32_bf16((a), (b), (c), 0, 0, 0)

static __device__ __forceinline__ u16 f2bf(float x) {
    u32 u = __builtin_bit_cast(u32, x);
    return (u16)((u + 0x7FFFu + ((u >> 16) & 1u)) >> 16);
}

// ---------------- preconv kernels ----------------

// Q-side scale fold: stage Q * (log2e / sqrt(128)) so softmax exp becomes a
// bare exp2f (native v_exp_f32), no per-element multiply in the hot loop.
#define QSCALE 0.12751743f

__global__ void k_transpose_bf16(const float* __restrict__ in, u16* __restrict__ out) {
    __shared__ float tile[32][33];
    const int obj = blockIdx.z;
    const float* src = in + (size_t)obj * D_K * BANK;
    u16* dst = out + (size_t)obj * BANK * D_K;
    const int bx = blockIdx.x * 32;   // bank
    const int by = blockIdx.y * 32;   // d
    const int tx = threadIdx.x, ty = threadIdx.y;  // 32 x 8
#pragma unroll
    for (int i = 0; i < 4; i++)
        tile[ty + 8 * i][tx] = src[(size_t)(by + ty + 8 * i) * BANK + bx + tx];
    __syncthreads();
#pragma unroll
    for (int i = 0; i < 4; i++)
        dst[(size_t)(bx + ty + 8 * i) * D_K + by + tx] = f2bf(tile[tx][ty + 8 * i]);
}

__global__ void k_convert_bf16(const float* __restrict__ in, u16* __restrict__ out, int n4) {
    int idx = blockIdx.x * blockDim.x + threadIdx.x;
    int stride = gridDim.x * blockDim.x;
    for (int i = idx; i < n4; i += stride) {
        float4 v = reinterpret_cast<const float4*>(in)[i];
        ushort4 o;
        o.x = f2bf(v.x); o.y = f2bf(v.y); o.z = f2bf(v.z); o.w = f2bf(v.w);
        reinterpret_cast<ushort4*>(out)[i] = o;
    }
}

__global__ void k_zero(float* out, int n) {
    int i = blockIdx.x * blockDim.x + threadIdx.x;
    if (i < n) out[i] = 0.f;
}

// ---------------- main fused kernel ----------------
// blockIdx.x = ((tile*G + g) << 3) | (o*2+vh): (o,vh) pinned per XCD for L2.
// launch_bounds(256,2): occupancy is structurally 2 blocks/CU (129-256
// unified-reg band); cap 256 gives the allocator headroom — no spill.
//
// ONE barrier per 64-bank unit: phase u computes QK(u) into P[cur] AND
// PV(u-1) from P[prev] (P double-buffered), then waits vmcnt(0)+lgkmcnt(0)
// and barriers. K gll for unit u+1 is issued at the top of phase u.
__launch_bounds__(256, 2)
__global__ void k_matcher(const u16* __restrict__ Kt,     // [O][7200][128] bf16
                          const u16* __restrict__ Vb,     // [O][512][7200] bf16
                          const float* __restrict__ masks,// [O][7200]
                          const float* __restrict__ q_in, // [128][3600]
                          const float* __restrict__ q_out,// [512][3600]
                          float* __restrict__ out,        // [O][1024][3600]
                          int G, float* __restrict__ lw, float* __restrict__ mw)
{
    __shared__ __align__(16) char smem[SMEM_BYTES];
    const int tid  = threadIdx.x;
    const int wave = tid >> 6;
    const int lane = tid & 63;
    const int q    = lane >> 4;
    const int lr   = lane & 15;
    const int lr7  = lr & 7;

    const int grp  = blockIdx.x & 7;
    const int o    = grp >> 1;
    const int vh   = grp & 1;
    const int rest = blockIdx.x >> 3;
    const int tile = rest / G;
    const int g    = rest - tile * G;
    const int n0   = tile * NT;

    // sub-tile (32-bank) range for this g; units = doubles (64) + optional tail (32)
    const int st0 = (NSUB * g) / G;
    const int st1 = (NSUB * (g + 1)) / G;
    const int cnt = st1 - st0;
    const int nd  = cnt >> 1;
    const int ts  = cnt & 1;
    const int nu  = nd + ts;

    // ---- stage Q tile (pre-scaled): Q_lds[n][d] bf16, granule swizzle ^ (n&7)
    for (int idx = tid; idx < NT * D_K; idx += 256) {
        int d = idx >> 6;
        int n = idx & 63;
        int gn = n0 + n;
        float v = (gn < NQ) ? q_in[(size_t)d * NQ + gn] * QSCALE : 0.f;
        int bb = d * 2;
        int sb = n * 256 + ((((bb >> 4) ^ (n & 7)) << 4) | (bb & 15));
        *reinterpret_cast<u16*>(smem + Q_OFF + sb) = f2bf(v);
    }
    __syncthreads();

    bf16x8 qf[4];
    {
        const int n = 16 * wave + lr;
#pragma unroll
        for (int ds = 0; ds < 4; ds++) {
            int gq = (4 * ds + q) ^ (n & 7);
            qf[ds] = *reinterpret_cast<const bf16x8*>(smem + Q_OFF + n * 256 + gq * 16);
        }
    }
    __syncthreads();   // Q region about to be overwritten by K staging

    const f32x4 zero4 = {0.f, 0.f, 0.f, 0.f};
    f32x4 acc[4][4];
#pragma unroll
    for (int i = 0; i < 4; i++)
#pragma unroll
        for (int j = 0; j < 4; j++) acc[i][j] = zero4;
    float l_part = 0.f, mm_part = 0.f;

    const u16* Ko = Kt + (size_t)o * BANK * D_K;
    const u16* Vo = Vb + (size_t)o * D_V * BANK + (size_t)vh * VH_ROWS * BANK;
    const float* mPtr = masks + (size_t)o * BANK + st0 * 32 + 4 * q;

    // K gll source pointers (pre-permuted; LDS dest linear) — see R7 notes.
    const u16* kSrcA = Ko + (size_t)(st0 * 32 + (tid >> 4)) * D_K
                         + (((tid & 15) ^ ((tid >> 4) & 7)) << 3);
    const u16* kSrcB = kSrcA + 16 * D_K;

#define ISSUE2(buf) do {                                                   \
        char* kb_ = smem + K_OFF + (buf) * 16384 + wave * 1024;            \
        GLL(kSrcA, kb_);                                                   \
        GLL(kSrcB, kb_ + 4096);                                            \
        GLL(kSrcA + 32 * D_K, kb_ + 8192);                                 \
        GLL(kSrcB + 32 * D_K, kb_ + 12288);                                \
        kSrcA += 64 * D_K; kSrcB += 64 * D_K;                              \
    } while (0)
#define ISSUE1(buf) do {                                                   \
        char* kb_ = smem + K_OFF + (buf) * 16384 + wave * 1024;            \
        GLL(kSrcA, kb_);                                                   \
        GLL(kSrcB, kb_ + 4096);                                            \
    } while (0)

    // V direct-to-register: uniform advancing base + per-lane offset.
    const u16* Vrow = Vo + st0 * 32;
    const u32  vOff = (u32)(64 * wave + lr) * BANK + q * 8;

    const int nrow  = 16 * wave + lr;       // this wave's P row

// QK^T for one 16-bank strip T (0..3): 4 MFMA, exp2 (scale pre-folded into Q),
// l/mm accumulate, cvt_pk -> bf16 pair, single b64 write into P[cur].
#define QK_T(T, MV, PWB) do {                                                \
        f32x4 s_acc = zero4;                                                 \
        const int b_r = 16 * (T) + lr;                                       \
        _Pragma("unroll")                                                    \
        for (int ds = 0; ds < 4; ds++) {                                     \
            bf16x8 kf = *reinterpret_cast<const bf16x8*>(                    \
                kb + b_r * 256 + (((4 * ds + q) ^ lr7) << 4));               \
            s_acc = MFMA16(kf, qf[ds], s_acc);                               \
        }                                                                    \
        float p0 = exp2f(s_acc[0]);                                          \
        float p1 = exp2f(s_acc[1]);                                          \
        float p2 = exp2f(s_acc[2]);                                          \
        float p3 = exp2f(s_acc[3]);                                          \
        l_part  += p0 + p1 + p2 + p3;                                        \
        mm_part += p0 * (MV).x + p1 * (MV).y + p2 * (MV).z + p3 * (MV).w;    \
        u32 w0, w1;                                                          \
        asm("v_cvt_pk_bf16_f32 %0, %1, %2" : "=v"(w0) : "v"(p0), "v"(p1));   \
        asm("v_cvt_pk_bf16_f32 %0, %1, %2" : "=v"(w1) : "v"(p2), "v"(p3));   \
        uint2 pk2; pk2.x = w0; pk2.y = w1;                                   \
        *reinterpret_cast<uint2*>(                                           \
            (PWB) + (((2 * (T) + (q >> 1)) ^ lr7) << 4)) = pk2;              \
    } while (0)

// PV for one 32-bank sub S from P buffer PB with V frags V0..V3
#define PV_S(S, PB, V0, V1, V2, V3) do {                                     \
        _Pragma("unroll")                                                    \
        for (int ng = 0; ng < 4; ng++) {                                     \
            bf16x8 pf = *reinterpret_cast<const bf16x8*>(                    \
                (PB) + (16 * ng + lr) * 128 +                                \
                (((4 * (S) + q) ^ lr7) << 4));                               \
            acc[0][ng] = MFMA16(V0, pf, acc[0][ng]);                         \
            acc[1][ng] = MFMA16(V1, pf, acc[1][ng]);                         \
            acc[2][ng] = MFMA16(V2, pf, acc[2][ng]);                         \
            acc[3][ng] = MFMA16(V3, pf, acc[3][ng]);                         \
        }                                                                    \
    } while (0)

    // ---- prologue: stage unit 0, wait, barrier
    if (nd > 0) ISSUE2(0); else ISSUE1(0);
    asm volatile("s_waitcnt vmcnt(0)" ::: "memory");
    __builtin_amdgcn_s_barrier();
    __builtin_amdgcn_sched_barrier(0);

    bf16x8 va0, va1, va2, va3, vb0, vb1, vb2, vb3;

    for (int u = 0; u < nu; u++) {
        const int cur = u & 1;
        const char* kb = smem + K_OFF + cur * 16384;
        char* pWc = smem + P_OFF + cur * 8192 + nrow * 128 + (q & 1) * 8;
        const char* pR = smem + P_OFF + (cur ^ 1) * 8192;
        const bool full = (u < nd);

        // stage next K tile (into buf cur^1; current readers use buf cur)
        if (u + 1 < nu) {
            if (u + 1 < nd) ISSUE2(cur ^ 1);
            else            ISSUE1(cur ^ 1);
        }

        // ---- QK(u) into P[cur]
        float4 mv0 = *reinterpret_cast<const float4*>(mPtr);
        float4 mv1 = *reinterpret_cast<const float4*>(mPtr + 16);
        QK_T(0, mv0, pWc);
        QK_T(1, mv1, pWc);
        if (full) {
            float4 mv2 = *reinterpret_cast<const float4*>(mPtr + 32);
            float4 mv3 = *reinterpret_cast<const float4*>(mPtr + 48);
            QK_T(2, mv2, pWc);
            QK_T(3, mv3, pWc);
        }

        // ---- V frags for unit u (fresh temps; consumed next phase/epilogue)
        bf16x8 na0 = *reinterpret_cast<const bf16x8*>(Vrow + vOff);
        bf16x8 na1 = *reinterpret_cast<const bf16x8*>(Vrow + vOff + 16 * BANK);
        bf16x8 na2 = *reinterpret_cast<const bf16x8*>(Vrow + vOff + 32 * BANK);
        bf16x8 na3 = *reinterpret_cast<const bf16x8*>(Vrow + vOff + 48 * BANK);
        bf16x8 nb0 = vb0, nb1 = vb1, nb2 = vb2, nb3 = vb3;
        if (full) {
            nb0 = *reinterpret_cast<const bf16x8*>(Vrow + vOff + 32);
            nb1 = *reinterpret_cast<const bf16x8*>(Vrow + vOff + 32 + 16 * BANK);
            nb2 = *reinterpret_cast<const bf16x8*>(Vrow + vOff + 32 + 32 * BANK);
            nb3 = *reinterpret_cast<const bf16x8*>(Vrow + vOff + 32 + 48 * BANK);
        }

        // ---- PV(u-1) from P[prev] (prev unit is always a full 64-bank unit)
        if (u > 0) {
            PV_S(0, pR, va0, va1, va2, va3);
            PV_S(1, pR, vb0, vb1, vb2, vb3);
        }
        va0 = na0; va1 = na1; va2 = na2; va3 = na3;
        vb0 = nb0; vb1 = nb1; vb2 = nb2; vb3 = nb3;

        mPtr += full ? 64 : 32;
        Vrow += full ? 64 : 32;

        // ---- end fence: my gll + V loads done, P[cur] writes visible
        asm volatile("s_waitcnt vmcnt(0) lgkmcnt(0)" ::: "memory");
        __builtin_amdgcn_s_barrier();
        __builtin_amdgcn_sched_barrier(0);
    }

    // ---- epilogue PV for the last unit
    {
        const char* pL = smem + P_OFF + ((nu - 1) & 1) * 8192;
        PV_S(0, pL, va0, va1, va2, va3);
        if (!ts) PV_S(1, pL, vb0, vb1, vb2, vb3);
    }

    // ---- finalize l, mm
    l_part  += __shfl_xor(l_part, 16);  l_part  += __shfl_xor(l_part, 32);
    mm_part += __shfl_xor(mm_part, 16); mm_part += __shfl_xor(mm_part, 32);
    float* l_lds  = reinterpret_cast<float*>(smem + LMM_OFF);
    float* mm_lds = l_lds + 64;
    if (lane < 16) {
        l_lds[16 * wave + lr]  = l_part;
        mm_lds[16 * wave + lr] = mm_part;
    }
    __syncthreads();

    if (G == 1) {
        // ---- final epilogue: mem = acc/l ; gated = q_out * (mm/l)
        float* outo = out + (size_t)o * (1024 * NQ);
#pragma unroll
        for (int ng = 0; ng < 4; ng++) {
            const int n  = 16 * ng + lr;
            const int gn = n0 + n;
            if (gn >= NQ) continue;
            const float invl = 1.f / l_lds[n];
            const float gate = mm_lds[n] * invl;
#pragma unroll
            for (int vt = 0; vt < 4; vt++) {
#pragma unroll
                for (int r = 0; r < 4; r++) {
                    const int v = vh * VH_ROWS + 64 * wave + 16 * vt + 4 * q + r;
                    outo[(size_t)v * NQ + gn] = acc[vt][ng][r] * invl;
                    outo[(size_t)(512 + v) * NQ + gn] = q_out[(size_t)v * NQ + gn] * gate;
                }
            }
        }
    } else {
        // ---- partial epilogue: raw acc into out rows [g*512 .. g*512+511]
        float* dst = out + ((size_t)o * 1024 + (size_t)g * 512 + (size_t)vh * VH_ROWS) * NQ;
#pragma unroll
        for (int ng = 0; ng < 4; ng++) {
            const int n  = 16 * ng + lr;
            const int gn = n0 + n;
            if (gn >= NQ) continue;
#pragma unroll
            for (int vt = 0; vt < 4; vt++) {
#pragma unroll
                for (int r = 0; r < 4; r++) {
                    const int v = 64 * wave + 16 * vt + 4 * q + r;
                    dst[(size_t)v * NQ + gn] = acc[vt][ng][r];
                }
            }
        }
        if (vh == 0 && tid < 64) {
            const size_t li = ((size_t)(g * 4 + o) * NTILES + tile) * 64 + tid;
            lw[li] = l_lds[tid];
            mw[li] = mm_lds[tid];
        }
    }
}

// ---------------- combine pass (G=2) ----------------
__global__ void k_combine(const float* __restrict__ q_out, const float* __restrict__ lw,
                          const float* __restrict__ mw, float* __restrict__ out) {
    const int total = O_N * 512 * (NQ / 4);   // float4 elements per half-row set
    float4* outv = reinterpret_cast<float4*>(out);
    const float4* qv = reinterpret_cast<const float4*>(q_out);
    for (int idx = blockIdx.x * blockDim.x + threadIdx.x; idx < total;
         idx += gridDim.x * blockDim.x) {
        const int o  = idx / (512 * 900);
        const int r  = idx - o * 512 * 900;
        const int v  = r / 900;
        const int g4 = r - v * 900;
        const size_t iA = ((size_t)o * 1024 + v) * 900 + g4;
        const size_t iB = ((size_t)o * 1024 + 512 + v) * 900 + g4;
        float4 A = outv[iA];
        float4 B = outv[iB];
        const int tl = g4 >> 4;
        const int wi = (g4 & 15) * 4;
        const size_t l0i = ((size_t)(0 * 4 + o) * NTILES + tl) * 64 + wi;
        const size_t l1i = ((size_t)(1 * 4 + o) * NTILES + tl) * 64 + wi;
        const float4 l0 = *reinterpret_cast<const float4*>(lw + l0i);
        const float4 l1 = *reinterpret_cast<const float4*>(lw + l1i);
        const float4 m0 = *reinterpret_cast<const float4*>(mw + l0i);
        const float4 m1 = *reinterpret_cast<const float4*>(mw + l1i);
        float4 li, mem, gate;
        li.x = 1.f / (l0.x + l1.x); li.y = 1.f / (l0.y + l1.y);
        li.z = 1.f / (l0.z + l1.z); li.w = 1.f / (l0.w + l1.w);
        mem.x = (A.x + B.x) * li.x; mem.y = (A.y + B.y) * li.y;
        mem.z = (A.z + B.z) * li.z; mem.w = (A.w + B.w) * li.w;
        gate.x = (m0.x + m1.x) * li.x; gate.y = (m0.y + m1.y) * li.y;
        gate.z = (m0.z + m1.z) * li.z; gate.w = (m0.w + m1.w) * li.w;
        float4 qo = qv[(size_t)v * 900 + g4];
        outv[iA] = mem;
        float4 gq;
        gq.x = qo.x * gate.x; gq.y = qo.y * gate.y;
        gq.z = qo.z * gate.z; gq.w = qo.w * gate.w;
        outv[iB] = gq;
    }
}

extern "C" void kernel_launch(void* const* d_in, const int* in_sizes, int n_in,
                              void* d_out, int out_size, void* d_ws, size_t ws_size,
                              hipStream_t stream) {
    const float* keys   = (const float*)d_in[0];
    const float* values = (const float*)d_in[1];
    const float* masks  = (const float*)d_in[2];
    const float* q_in   = (const float*)d_in[3];
    const float* q_outp = (const float*)d_in[4];
    float* out = (float*)d_out;

    const size_t K_BYTES  = (size_t)O_N * BANK * D_K * 2;   //  7,372,800
    const size_t V_BYTES  = (size_t)O_N * D_V * BANK * 2;   // 29,491,200
    const size_t LM_FLOATS = (size_t)2 * O_N * NTILES * 64; // per array (G=2)
    const size_t LM_BYTES  = LM_FLOATS * 4 * 2;             // l + mm

    if (ws_size < K_BYTES + V_BYTES) {
        k_zero<<<(out_size + 255) / 256, 256, 0, stream>>>(out, out_size);
        return;
    }
    const int G = (ws_size >= K_BYTES + V_BYTES + LM_BYTES) ? 2 : 1;

    u16* Kt = (u16*)d_ws;
    u16* Vb = (u16*)((char*)d_ws + K_BYTES);
    float* lw = (float*)((char*)d_ws + K_BYTES + V_BYTES);
    float* mw = lw + LM_FLOATS;

    dim3 tb(32, 8);
    dim3 tg(BANK / 32, D_K / 32, O_N);
    k_transpose_bf16<<<tg, tb, 0, stream>>>(keys, Kt);

    const int n4 = O_N * D_V * BANK / 4;
    k_convert_bf16<<<2048, 256, 0, stream>>>(values, Vb, n4);

    k_matcher<<<NTILES * 8 * G, 256, 0, stream>>>(Kt, Vb, masks, q_in, q_outp, out,
                                                  G, lw, mw);
    if (G == 2)
        k_combine<<<2048, 256, 0, stream>>>(q_outp, lw, mw, out);
}

// Round 9
// 294.557 us; speedup vs baseline: 1.1450x; 1.1450x over previous
//
#include <hip/hip_runtime.h>
#include <hip/hip_bf16.h>

typedef unsigned short u16;
typedef unsigned int   u32;
typedef short bf16x8 __attribute__((ext_vector_type(8)));
typedef float f32x4  __attribute__((ext_vector_type(4)));

#define O_N    4
#define D_K    128
#define D_V    512
#define BANK   7200
#define NQ     3600
#define NT     64            // query columns per block
#define NTILES 57            // ceil(3600/64)
#define NSUB   225           // 7200 / 32 sub-tiles
#define VH_ROWS 256          // v rows per block (half of 512)

// ---- LDS layout (bytes)
#define K_OFF    0           // K dbuf: 2 x [64 b][128 d] bf16 (2 x 16384)
#define P_OFF    32768       // P dbuf: 2 x [64 n][64 b] bf16, 128B rows (2 x 8192)
#define LMM_OFF  49152       // l[64], mm[64] f32 (512)
#define SMEM_BYTES 49664
#define Q_OFF    0           // Q tile [64 n][128 d] bf16 (16KB) overlaps K buf0; prologue only

// global_load_lds: linear LDS dest (wave base + lane*16); source address is
// pre-permuted per-lane so READ-side swizzle formulas keep working.
// NOTE: imm offset is 13-bit SIGNED (max +4095) — keep 0, explicit addresses.
#define GLL(gsrc, ldst) __builtin_amdgcn_global_load_lds( \
    (const __attribute__((address_space(1))) void*)(gsrc), \
    (__attribute__((address_space(3))) void*)(ldst), 16, 0, 0)

#define MFMA16(a, b, c) __builtin_amdgcn_mfma_f32_16x16x32_bf16((a), (b), (c), 0, 0, 0)

static __device__ __forceinline__ u16 f2bf(float x) {
    u32 u = __builtin_bit_cast(u32, x);
    return (u16)((u + 0x7FFFu + ((u >> 16) & 1u)) >> 16);
}

// ---------------- preconv kernels ----------------

// Q-side scale fold: stage Q * (log2e / sqrt(128)) so softmax exp becomes a
// bare exp2f (native v_exp_f32), no per-element multiply in the hot loop.
#define QSCALE 0.12751743f

__global__ void k_transpose_bf16(const float* __restrict__ in, u16* __restrict__ out) {
    __shared__ float tile[32][33];
    const int obj = blockIdx.z;
    const float* src = in + (size_t)obj * D_K * BANK;
    u16* dst = out + (size_t)obj * BANK * D_K;
    const int bx = blockIdx.x * 32;   // bank
    const int by = blockIdx.y * 32;   // d
    const int tx = threadIdx.x, ty = threadIdx.y;  // 32 x 8
#pragma unroll
    for (int i = 0; i < 4; i++)
        tile[ty + 8 * i][tx] = src[(size_t)(by + ty + 8 * i) * BANK + bx + tx];
    __syncthreads();
#pragma unroll
    for (int i = 0; i < 4; i++)
        dst[(size_t)(bx + ty + 8 * i) * D_K + by + tx] = f2bf(tile[tx][ty + 8 * i]);
}

__global__ void k_convert_bf16(const float* __restrict__ in, u16* __restrict__ out, int n4) {
    int idx = blockIdx.x * blockDim.x + threadIdx.x;
    int stride = gridDim.x * blockDim.x;
    for (int i = idx; i < n4; i += stride) {
        float4 v = reinterpret_cast<const float4*>(in)[i];
        ushort4 o;
        o.x = f2bf(v.x); o.y = f2bf(v.y); o.z = f2bf(v.z); o.w = f2bf(v.w);
        reinterpret_cast<ushort4*>(out)[i] = o;
    }
}

__global__ void k_zero(float* out, int n) {
    int i = blockIdx.x * blockDim.x + threadIdx.x;
    if (i < n) out[i] = 0.f;
}

// ---------------- main fused kernel ----------------
// blockIdx.x = ((tile*G + g) << 3) | (o*2+vh): (o,vh) pinned per XCD for L2.
// launch_bounds(256,2): occupancy is structurally 2 blocks/CU (129-256
// unified-reg band); cap 256 gives the allocator headroom — no spill.
//
// ONE barrier per 64-bank unit. Phase u VMEM issue order (pinned by
// sched_barrier): [V(u) frags + masks(u)] then [K gll(u+1)]. The end fence
// vmcnt(0) therefore waits on loads that have had the WHOLE phase to
// complete (V issued at top; gll window = QK+PV). R8's regression was V
// issued late and drained immediately at the fence.
__launch_bounds__(256, 2)
__global__ void k_matcher(const u16* __restrict__ Kt,     // [O][7200][128] bf16
                          const u16* __restrict__ Vb,     // [O][512][7200] bf16
                          const float* __restrict__ masks,// [O][7200]
                          const float* __restrict__ q_in, // [128][3600]
                          const float* __restrict__ q_out,// [512][3600]
                          float* __restrict__ out,        // [O][1024][3600]
                          int G, float* __restrict__ lw, float* __restrict__ mw)
{
    __shared__ __align__(16) char smem[SMEM_BYTES];
    const int tid  = threadIdx.x;
    const int wave = tid >> 6;
    const int lane = tid & 63;
    const int q    = lane >> 4;
    const int lr   = lane & 15;
    const int lr7  = lr & 7;

    const int grp  = blockIdx.x & 7;
    const int o    = grp >> 1;
    const int vh   = grp & 1;
    const int rest = blockIdx.x >> 3;
    const int tile = rest / G;
    const int g    = rest - tile * G;
    const int n0   = tile * NT;

    // sub-tile (32-bank) range for this g; units = doubles (64) + optional tail (32)
    const int st0 = (NSUB * g) / G;
    const int st1 = (NSUB * (g + 1)) / G;
    const int cnt = st1 - st0;
    const int nd  = cnt >> 1;
    const int ts  = cnt & 1;
    const int nu  = nd + ts;

    // ---- stage Q tile (pre-scaled): Q_lds[n][d] bf16, granule swizzle ^ (n&7)
    for (int idx = tid; idx < NT * D_K; idx += 256) {
        int d = idx >> 6;
        int n = idx & 63;
        int gn = n0 + n;
        float v = (gn < NQ) ? q_in[(size_t)d * NQ + gn] * QSCALE : 0.f;
        int bb = d * 2;
        int sb = n * 256 + ((((bb >> 4) ^ (n & 7)) << 4) | (bb & 15));
        *reinterpret_cast<u16*>(smem + Q_OFF + sb) = f2bf(v);
    }
    __syncthreads();

    bf16x8 qf[4];
    {
        const int n = 16 * wave + lr;
#pragma unroll
        for (int ds = 0; ds < 4; ds++) {
            int gq = (4 * ds + q) ^ (n & 7);
            qf[ds] = *reinterpret_cast<const bf16x8*>(smem + Q_OFF + n * 256 + gq * 16);
        }
    }
    __syncthreads();   // Q region about to be overwritten by K staging

    const f32x4 zero4 = {0.f, 0.f, 0.f, 0.f};
    f32x4 acc[4][4];
#pragma unroll
    for (int i = 0; i < 4; i++)
#pragma unroll
        for (int j = 0; j < 4; j++) acc[i][j] = zero4;
    float l_part = 0.f, mm_part = 0.f;

    const u16* Ko = Kt + (size_t)o * BANK * D_K;
    const u16* Vo = Vb + (size_t)o * D_V * BANK + (size_t)vh * VH_ROWS * BANK;
    const float* mPtr = masks + (size_t)o * BANK + st0 * 32 + 4 * q;

    // K gll source pointers, pre-permuted with 4-BIT key: slot s of row b
    // holds granule s ^ (b&15)  (was b&7: only 8 distinct granules -> 8 lanes
    // per bank-quad on frag reads; 4-bit key halves that to 4).
    // (row+16)&15 == row&15 shifted consistently -> kSrcB = kSrcA + 16*D_K,
    // and +32 rows for the second half of a 64-bank tile.
    const u16* kSrcA = Ko + (size_t)(st0 * 32 + (tid >> 4)) * D_K
                         + (((tid & 15) ^ (tid >> 4)) << 3);
    const u16* kSrcB = kSrcA + 16 * D_K;

#define ISSUE2(buf) do {                                                   \
        char* kb_ = smem + K_OFF + (buf) * 16384 + wave * 1024;            \
        GLL(kSrcA, kb_);                                                   \
        GLL(kSrcB, kb_ + 4096);                                            \
        GLL(kSrcA + 32 * D_K, kb_ + 8192);                                 \
        GLL(kSrcB + 32 * D_K, kb_ + 12288);                                \
        kSrcA += 64 * D_K; kSrcB += 64 * D_K;                              \
    } while (0)
#define ISSUE1(buf) do {                                                   \
        char* kb_ = smem + K_OFF + (buf) * 16384 + wave * 1024;            \
        GLL(kSrcA, kb_);                                                   \
        GLL(kSrcB, kb_ + 4096);                                            \
    } while (0)

    // V direct-to-register: uniform advancing base + per-lane offset.
    const u16* Vrow = Vo + st0 * 32;
    const u32  vOff = (u32)(64 * wave + lr) * BANK + q * 8;

    const int nrow  = 16 * wave + lr;       // this wave's P row

// QK^T for one 16-bank strip T (0..3): 4 MFMA (K read swizzle uses 4-bit lr
// key), exp2 (scale pre-folded into Q), l/mm accumulate, cvt_pk, b64 P write.
#define QK_T(T, MV, PWB) do {                                                \
        f32x4 s_acc = zero4;                                                 \
        const int b_r = 16 * (T) + lr;                                       \
        _Pragma("unroll")                                                    \
        for (int ds = 0; ds < 4; ds++) {                                     \
            bf16x8 kf = *reinterpret_cast<const bf16x8*>(                    \
                kb + b_r * 256 + (((4 * ds + q) ^ lr) << 4));                \
            s_acc = MFMA16(kf, qf[ds], s_acc);                               \
        }                                                                    \
        float p0 = exp2f(s_acc[0]);                                          \
        float p1 = exp2f(s_acc[1]);                                          \
        float p2 = exp2f(s_acc[2]);                                          \
        float p3 = exp2f(s_acc[3]);                                          \
        l_part  += p0 + p1 + p2 + p3;                                        \
        mm_part += p0 * (MV).x + p1 * (MV).y + p2 * (MV).z + p3 * (MV).w;    \
        u32 w0, w1;                                                          \
        asm("v_cvt_pk_bf16_f32 %0, %1, %2" : "=v"(w0) : "v"(p0), "v"(p1));   \
        asm("v_cvt_pk_bf16_f32 %0, %1, %2" : "=v"(w1) : "v"(p2), "v"(p3));   \
        uint2 pk2; pk2.x = w0; pk2.y = w1;                                   \
        *reinterpret_cast<uint2*>(                                           \
            (PWB) + (((2 * (T) + (q >> 1)) ^ lr7) << 4)) = pk2;              \
    } while (0)

// PV for one 32-bank sub S from P buffer PB with V frags V0..V3
#define PV_S(S, PB, V0, V1, V2, V3) do {                                     \
        _Pragma("unroll")                                                    \
        for (int ng = 0; ng < 4; ng++) {                                     \
            bf16x8 pf = *reinterpret_cast<const bf16x8*>(                    \
                (PB) + (16 * ng + lr) * 128 +                                \
                (((4 * (S) + q) ^ lr7) << 4));                               \
            acc[0][ng] = MFMA16(V0, pf, acc[0][ng]);                         \
            acc[1][ng] = MFMA16(V1, pf, acc[1][ng]);                         \
            acc[2][ng] = MFMA16(V2, pf, acc[2][ng]);                         \
            acc[3][ng] = MFMA16(V3, pf, acc[3][ng]);                         \
        }                                                                    \
    } while (0)

    // ---- prologue: stage unit 0, wait, barrier
    if (nd > 0) ISSUE2(0); else ISSUE1(0);
    asm volatile("s_waitcnt vmcnt(0)" ::: "memory");
    __builtin_amdgcn_s_barrier();
    __builtin_amdgcn_sched_barrier(0);

    bf16x8 va0, va1, va2, va3, vb0, vb1, vb2, vb3;

    for (int u = 0; u < nu; u++) {
        const int cur = u & 1;
        const char* kb = smem + K_OFF + cur * 16384;
        char* pWc = smem + P_OFF + cur * 8192 + nrow * 128 + (q & 1) * 8;
        const char* pR = smem + P_OFF + (cur ^ 1) * 8192;
        const bool full = (u < nd);

        // ---- issue FIRST: this unit's V frags + masks (complete long before
        // the end-of-phase fence; consumed in PV next phase / QK this phase)
        float4 mv0 = *reinterpret_cast<const float4*>(mPtr);
        float4 mv1 = *reinterpret_cast<const float4*>(mPtr + 16);
        float4 mv2, mv3;
        bf16x8 na0 = *reinterpret_cast<const bf16x8*>(Vrow + vOff);
        bf16x8 na1 = *reinterpret_cast<const bf16x8*>(Vrow + vOff + 16 * BANK);
        bf16x8 na2 = *reinterpret_cast<const bf16x8*>(Vrow + vOff + 32 * BANK);
        bf16x8 na3 = *reinterpret_cast<const bf16x8*>(Vrow + vOff + 48 * BANK);
        bf16x8 nb0 = vb0, nb1 = vb1, nb2 = vb2, nb3 = vb3;
        if (full) {
            mv2 = *reinterpret_cast<const float4*>(mPtr + 32);
            mv3 = *reinterpret_cast<const float4*>(mPtr + 48);
            nb0 = *reinterpret_cast<const bf16x8*>(Vrow + vOff + 32);
            nb1 = *reinterpret_cast<const bf16x8*>(Vrow + vOff + 32 + 16 * BANK);
            nb2 = *reinterpret_cast<const bf16x8*>(Vrow + vOff + 32 + 32 * BANK);
            nb3 = *reinterpret_cast<const bf16x8*>(Vrow + vOff + 32 + 48 * BANK);
        }
        __builtin_amdgcn_sched_barrier(0);   // V/mask issue stays ABOVE gll

        // ---- then next K tile staging (newest VMEM; fence below drains it
        // after a full phase of overlap)
        if (u + 1 < nu) {
            if (u + 1 < nd) ISSUE2(cur ^ 1);
            else            ISSUE1(cur ^ 1);
        }
        __builtin_amdgcn_sched_barrier(0);   // gll stays ABOVE compute

        // ---- QK(u) into P[cur]
        QK_T(0, mv0, pWc);
        QK_T(1, mv1, pWc);
        if (full) {
            QK_T(2, mv2, pWc);
            QK_T(3, mv3, pWc);
        }

        // ---- PV(u-1) from P[prev] (prev unit is always a full 64-bank unit)
        if (u > 0) {
            PV_S(0, pR, va0, va1, va2, va3);
            PV_S(1, pR, vb0, vb1, vb2, vb3);
        }
        va0 = na0; va1 = na1; va2 = na2; va3 = na3;
        vb0 = nb0; vb1 = nb1; vb2 = nb2; vb3 = nb3;

        mPtr += full ? 64 : 32;
        Vrow += full ? 64 : 32;

        // ---- end fence: P[cur] visible; all my VMEM (V, masks, gll) done —
        // everything was issued at phase top, so this drain is cheap.
        asm volatile("s_waitcnt vmcnt(0) lgkmcnt(0)" ::: "memory");
        __builtin_amdgcn_s_barrier();
        __builtin_amdgcn_sched_barrier(0);
    }

    // ---- epilogue PV for the last unit
    {
        const char* pL = smem + P_OFF + ((nu - 1) & 1) * 8192;
        PV_S(0, pL, va0, va1, va2, va3);
        if (!ts) PV_S(1, pL, vb0, vb1, vb2, vb3);
    }

    // ---- finalize l, mm
    l_part  += __shfl_xor(l_part, 16);  l_part  += __shfl_xor(l_part, 32);
    mm_part += __shfl_xor(mm_part, 16); mm_part += __shfl_xor(mm_part, 32);
    float* l_lds  = reinterpret_cast<float*>(smem + LMM_OFF);
    float* mm_lds = l_lds + 64;
    if (lane < 16) {
        l_lds[16 * wave + lr]  = l_part;
        mm_lds[16 * wave + lr] = mm_part;
    }
    __syncthreads();

    if (G == 1) {
        // ---- final epilogue: mem = acc/l ; gated = q_out * (mm/l)
        float* outo = out + (size_t)o * (1024 * NQ);
#pragma unroll
        for (int ng = 0; ng < 4; ng++) {
            const int n  = 16 * ng + lr;
            const int gn = n0 + n;
            if (gn >= NQ) continue;
            const float invl = 1.f / l_lds[n];
            const float gate = mm_lds[n] * invl;
#pragma unroll
            for (int vt = 0; vt < 4; vt++) {
#pragma unroll
                for (int r = 0; r < 4; r++) {
                    const int v = vh * VH_ROWS + 64 * wave + 16 * vt + 4 * q + r;
                    outo[(size_t)v * NQ + gn] = acc[vt][ng][r] * invl;
                    outo[(size_t)(512 + v) * NQ + gn] = q_out[(size_t)v * NQ + gn] * gate;
                }
            }
        }
    } else {
        // ---- partial epilogue: raw acc into out rows [g*512 .. g*512+511]
        float* dst = out + ((size_t)o * 1024 + (size_t)g * 512 + (size_t)vh * VH_ROWS) * NQ;
#pragma unroll
        for (int ng = 0; ng < 4; ng++) {
            const int n  = 16 * ng + lr;
            const int gn = n0 + n;
            if (gn >= NQ) continue;
#pragma unroll
            for (int vt = 0; vt < 4; vt++) {
#pragma unroll
                for (int r = 0; r < 4; r++) {
                    const int v = 64 * wave + 16 * vt + 4 * q + r;
                    dst[(size_t)v * NQ + gn] = acc[vt][ng][r];
                }
            }
        }
        if (vh == 0 && tid < 64) {
            const size_t li = ((size_t)(g * 4 + o) * NTILES + tile) * 64 + tid;
            lw[li] = l_lds[tid];
            mw[li] = mm_lds[tid];
        }
    }
}

// ---------------- combine pass (G=2) ----------------
__global__ void k_combine(const float* __restrict__ q_out, const float* __restrict__ lw,
                          const float* __restrict__ mw, float* __restrict__ out) {
    const int total = O_N * 512 * (NQ / 4);   // float4 elements per half-row set
    float4* outv = reinterpret_cast<float4*>(out);
    const float4* qv = reinterpret_cast<const float4*>(q_out);
    for (int idx = blockIdx.x * blockDim.x + threadIdx.x; idx < total;
         idx += gridDim.x * blockDim.x) {
        const int o  = idx / (512 * 900);
        const int r  = idx - o * 512 * 900;
        const int v  = r / 900;
        const int g4 = r - v * 900;
        const size_t iA = ((size_t)o * 1024 + v) * 900 + g4;
        const size_t iB = ((size_t)o * 1024 + 512 + v) * 900 + g4;
        float4 A = outv[iA];
        float4 B = outv[iB];
        const int tl = g4 >> 4;
        const int wi = (g4 & 15) * 4;
        const size_t l0i = ((size_t)(0 * 4 + o) * NTILES + tl) * 64 + wi;
        const size_t l1i = ((size_t)(1 * 4 + o) * NTILES + tl) * 64 + wi;
        const float4 l0 = *reinterpret_cast<const float4*>(lw + l0i);
        const float4 l1 = *reinterpret_cast<const float4*>(lw + l1i);
        const float4 m0 = *reinterpret_cast<const float4*>(mw + l0i);
        const float4 m1 = *reinterpret_cast<const float4*>(mw + l1i);
        float4 li, mem, gate;
        li.x = 1.f / (l0.x + l1.x); li.y = 1.f / (l0.y + l1.y);
        li.z = 1.f / (l0.z + l1.z); li.w = 1.f / (l0.w + l1.w);
        mem.x = (A.x + B.x) * li.x; mem.y = (A.y + B.y) * li.y;
        mem.z = (A.z + B.z) * li.z; mem.w = (A.w + B.w) * li.w;
        gate.x = (m0.x + m1.x) * li.x; gate.y = (m0.y + m1.y) * li.y;
        gate.z = (m0.z + m1.z) * li.z; gate.w = (m0.w + m1.w) * li.w;
        float4 qo = qv[(size_t)v * 900 + g4];
        outv[iA] = mem;
        float4 gq;
        gq.x = qo.x * gate.x; gq.y = qo.y * gate.y;
        gq.z = qo.z * gate.z; gq.w = qo.w * gate.w;
        outv[iB] = gq;
    }
}

extern "C" void kernel_launch(void* const* d_in, const int* in_sizes, int n_in,
                              void* d_out, int out_size, void* d_ws, size_t ws_size,
                              hipStream_t stream) {
    const float* keys   = (const float*)d_in[0];
    const float* values = (const float*)d_in[1];
    const float* masks  = (const float*)d_in[2];
    const float* q_in   = (const float*)d_in[3];
    const float* q_outp = (const float*)d_in[4];
    float* out = (float*)d_out;

    const size_t K_BYTES  = (size_t)O_N * BANK * D_K * 2;   //  7,372,800
    const size_t V_BYTES  = (size_t)O_N * D_V * BANK * 2;   // 29,491,200
    const size_t LM_FLOATS = (size_t)2 * O_N * NTILES * 64; // per array (G=2)
    const size_t LM_BYTES  = LM_FLOATS * 4 * 2;             // l + mm

    if (ws_size < K_BYTES + V_BYTES) {
        k_zero<<<(out_size + 255) / 256, 256, 0, stream>>>(out, out_size);
        return;
    }
    const int G = (ws_size >= K_BYTES + V_BYTES + LM_BYTES) ? 2 : 1;

    u16* Kt = (u16*)d_ws;
    u16* Vb = (u16*)((char*)d_ws + K_BYTES);
    float* lw = (float*)((char*)d_ws + K_BYTES + V_BYTES);
    float* mw = lw + LM_FLOATS;

    dim3 tb(32, 8);
    dim3 tg(BANK / 32, D_K / 32, O_N);
    k_transpose_bf16<<<tg, tb, 0, stream>>>(keys, Kt);

    const int n4 = O_N * D_V * BANK / 4;
    k_convert_bf16<<<2048, 256, 0, stream>>>(values, Vb, n4);

    k_matcher<<<NTILES * 8 * G, 256, 0, stream>>>(Kt, Vb, masks, q_in, q_outp, out,
                                                  G, lw, mw);
    if (G == 2)
        k_combine<<<2048, 256, 0, stream>>>(q_outp, lw, mw, out);
}